// Round 12
// baseline (594.176 us; speedup 1.0000x reference)
//
#include <hip/hip_runtime.h>
#include <math.h>

#define QN 4096
#define NN 1024
#define FD 64
#define HD 128
#define NBLK 1024

typedef float v2f __attribute__((ext_vector_type(2)));

// workspace layout (float offsets)
#define OFF_B     0        // B [1024 n][128 h]
#define OFF_VB    131072   // vb [1024]
#define OFF_L     132096   // L [1024 n][4096 q]
#define OFF_PM    4326400  // pm [64 tile][4096 q]
#define OFF_PART  4588544  // part [8 c][4096 q][64 f]
#define OFF_SPART 6685696  // spart [8 c][4096 q]
#define OFF_CNT   6718464  // barrier counter (1 u32)
// end: 6718480 floats ~= 26.9 MB

struct SmemP2 { float red[4][2][32][33]; float sred[4][33]; };
struct SmemP3 { float agg[4][64]; float inv[4]; float h1s[4][128]; };
union Smem {
  float ps[4];
  SmemP2 p2;
  SmemP3 p3;
};

// Grid barrier: relaxed spin (no per-poll cache invalidation), one
// acquire fence on exit. All NBLK blocks are co-resident by construction
// (__launch_bounds__(256,4) -> 4 blocks/CU x 256 CUs = 1024).
__device__ inline void grid_barrier(unsigned* cnt, unsigned target) {
  __syncthreads();
  if (threadIdx.x == 0) {
    __threadfence();   // release: make this block's writes device-visible
    __hip_atomic_fetch_add(cnt, 1u, __ATOMIC_RELEASE, __HIP_MEMORY_SCOPE_AGENT);
    while (__hip_atomic_load(cnt, __ATOMIC_RELAXED, __HIP_MEMORY_SCOPE_AGENT) < target) {
      __builtin_amdgcn_s_sleep(16);
    }
    __threadfence();   // acquire: invalidate once before reading others' writes
  }
  __syncthreads();
}

__global__ __launch_bounds__(256, 4) void fused_all(
    const float* __restrict__ qp, const float* __restrict__ nf,
    const float* __restrict__ npos, const float* __restrict__ aW1,
    const float* __restrict__ ab1, const float* __restrict__ aW2,
    const float* __restrict__ ab2, const float* __restrict__ dW1,
    const float* __restrict__ db1, const float* __restrict__ dW2,
    const float* __restrict__ db2,
    float* __restrict__ B, float* __restrict__ vb,
    float* __restrict__ L, float* __restrict__ pm,
    float* __restrict__ part, float* __restrict__ spart,
    unsigned* __restrict__ cnt, float* __restrict__ out) {
  __shared__ Smem sm;
  const int t = threadIdx.x;
  const int lane = t & 63, w = t >> 6;

  // ---------------- P0: B[n][h] + vb[n] (blocks 0..511 only) ----------------
  if (blockIdx.x < 512) {
    int i2 = blockIdx.x * 256 + t;
    int n = i2 >> 7, h = i2 & 127;
    float s = ab1[h];
    #pragma unroll
    for (int f = 0; f < FD; ++f) s = fmaf(nf[n*FD+f], aW1[f*HD+h], s);
    s -= npos[n*3+0] * aW1[(FD+0)*HD + h]
       + npos[n*3+1] * aW1[(FD+1)*HD + h]
       + npos[n*3+2] * aW1[(FD+2)*HD + h];
    B[i2] = s;
    float pv = s * aW2[h];
    #pragma unroll
    for (int m = 1; m < 64; m <<= 1) pv += __shfl_xor(pv, m, 64);
    if ((t & 63) == 0) sm.ps[t >> 6] = pv;
    __syncthreads();
    if (t == 0)   vb[n] = sm.ps[0] + sm.ps[1];
    if (t == 128) vb[n] = sm.ps[2] + sm.ps[3];
  }
  grid_barrier(cnt, NBLK);

  // ---------------- P1: logits; u computed on the fly; B via uniform loads --
  {
    const int tile = blockIdx.x;
    const int q = (tile & 15) * 256 + w * 64 + lane;
    const int n0 = (tile >> 4) * 16;
    const float qx = qp[q*3+0], qy = qp[q*3+1], qz = qp[q*3+2];

    float acc[16];
    #pragma unroll
    for (int nn = 0; nn < 16; ++nn) acc[nn] = 0.f;
    float vuq = 0.f;

    #pragma unroll 1
    for (int hc = 0; hc < 16; ++hc) {
      const float* w0  = aW1 + (FD+0)*HD + hc*8;   // uniform -> s_load
      const float* w1  = aW1 + (FD+1)*HD + hc*8;
      const float* w2  = aW1 + (FD+2)*HD + hc*8;
      const float* awp = aW2 + hc*8;               // uniform -> s_load
      float u0 = qx*w0[0] + qy*w1[0] + qz*w2[0];
      float u1 = qx*w0[1] + qy*w1[1] + qz*w2[1];
      float u2 = qx*w0[2] + qy*w1[2] + qz*w2[2];
      float u3 = qx*w0[3] + qy*w1[3] + qz*w2[3];
      float u4 = qx*w0[4] + qy*w1[4] + qz*w2[4];
      float u5 = qx*w0[5] + qy*w1[5] + qz*w2[5];
      float u6 = qx*w0[6] + qy*w1[6] + qz*w2[6];
      float u7 = qx*w0[7] + qy*w1[7] + qz*w2[7];
      float aw0 = awp[0], aw1 = awp[1], aw2 = awp[2], aw3 = awp[3];
      float aw4 = awp[4], aw5 = awp[5], aw6 = awp[6], aw7 = awp[7];
      vuq = fmaf(aw0, u0, vuq); vuq = fmaf(aw1, u1, vuq);
      vuq = fmaf(aw2, u2, vuq); vuq = fmaf(aw3, u3, vuq);
      vuq = fmaf(aw4, u4, vuq); vuq = fmaf(aw5, u5, vuq);
      vuq = fmaf(aw6, u6, vuq); vuq = fmaf(aw7, u7, vuq);
      #pragma unroll
      for (int nn = 0; nn < 16; ++nn) {
        const float* bp = B + (n0 + nn) * HD + hc * 8;  // uniform -> s_load
        float a = acc[nn];
        a = fmaf(aw0, __builtin_fabsf(u0 + bp[0]), a);
        a = fmaf(aw1, __builtin_fabsf(u1 + bp[1]), a);
        a = fmaf(aw2, __builtin_fabsf(u2 + bp[2]), a);
        a = fmaf(aw3, __builtin_fabsf(u3 + bp[3]), a);
        a = fmaf(aw4, __builtin_fabsf(u4 + bp[4]), a);
        a = fmaf(aw5, __builtin_fabsf(u5 + bp[5]), a);
        a = fmaf(aw6, __builtin_fabsf(u6 + bp[6]), a);
        a = fmaf(aw7, __builtin_fabsf(u7 + bp[7]), a);
        acc[nn] = a;
      }
    }

    const float bias2 = ab2[0];
    float m = -3.4e38f;
    #pragma unroll
    for (int nn = 0; nn < 16; ++nn) {
      int n = n0 + nn;
      float px = npos[n*3+0], py = npos[n*3+1];
      float vbn = vb[n];
      float dx = qx - px, dy = qy - py;
      float wgt = 1.f / (sqrtf(dx*dx + dy*dy) + 1e-6f);
      float score = fmaf(0.5f, vuq + vbn + acc[nn], bias2);
      float lg = score * wgt;
      L[n * QN + q] = lg;
      m = fmaxf(m, lg);
    }
    pm[(tile >> 4) * QN + q] = m;
  }
  grid_barrier(cnt, 2 * NBLK);

  // ---------------- P2: exp + partial aggregate (1 chunk/block) ----------------
  {
    int b = blockIdx.x;
    int qt = b & 127, c = b >> 7;        // c in [0,8)
    int qi = lane & 31, fh = lane >> 5;
    int q = qt * 32 + qi;

    float m = -3.4e38f;
    #pragma unroll
    for (int k = 0; k < 64; ++k) m = fmaxf(m, pm[k * QN + q]);

    float acc[32];
    #pragma unroll
    for (int f = 0; f < 32; ++f) acc[f] = 0.f;
    float s = 0.f;

    int nbase = c * 128 + w * 32;
    const float* Lp = L + (size_t)nbase * QN + q;
    float cur = *Lp;
    for (int i = 0; i < 32; ++i) {
      float nxt = (i < 31) ? Lp[(size_t)(i + 1) * QN] : 0.f;
      float p = exp2f((cur - m) * 1.44269504088896f);
      s += p;
      const float4* nfr = (const float4*)(nf + (nbase + i) * FD + fh * 32);
      #pragma unroll
      for (int g = 0; g < 8; ++g) {
        float4 a = nfr[g];
        acc[g*4+0] = fmaf(p, a.x, acc[g*4+0]);
        acc[g*4+1] = fmaf(p, a.y, acc[g*4+1]);
        acc[g*4+2] = fmaf(p, a.z, acc[g*4+2]);
        acc[g*4+3] = fmaf(p, a.w, acc[g*4+3]);
      }
      cur = nxt;
    }

    #pragma unroll
    for (int fi = 0; fi < 32; ++fi) sm.p2.red[w][fh][fi][qi] = acc[fi];
    if (fh == 0) sm.p2.sred[w][qi] = s;
    __syncthreads();
    #pragma unroll
    for (int k = 0; k < 8; ++k) {
      int idx = k * 256 + t;
      int qq = idx >> 6, f = idx & 63;
      int f1 = f >> 5, f0 = f & 31;
      float sum = sm.p2.red[0][f1][f0][qq] + sm.p2.red[1][f1][f0][qq]
                + sm.p2.red[2][f1][f0][qq] + sm.p2.red[3][f1][f0][qq];
      part[((size_t)c * QN + qt*32 + qq) * 64 + f] = sum;
    }
    if (t < 32) {
      spart[c * QN + qt*32 + t] = sm.p2.sred[0][t] + sm.p2.sred[1][t]
                                + sm.p2.sred[2][t] + sm.p2.sred[3][t];
    }
  }
  grid_barrier(cnt, 3 * NBLK);

  // ---------------- P3: reduce partials, normalize, decode (4 q/block) ------
  {
    int qb = blockIdx.x * 4;
    if (t < 4) {
      float s = 0.f;
      #pragma unroll
      for (int c = 0; c < 8; ++c) s += spart[c*QN + qb + t];
      sm.p3.inv[t] = 1.f / s;
    }
    {
      int f = t & 63, qs = t >> 6;   // qs in [0,4)
      float v = 0.f;
      #pragma unroll
      for (int c = 0; c < 8; ++c) v += part[((size_t)c*QN + qb + qs)*64 + f];
      sm.p3.agg[qs][f] = v;
    }
    __syncthreads();
    {
      int h = t & 127, qg = t >> 7;  // qg in [0,2)
      #pragma unroll
      for (int k = 0; k < 2; ++k) {
        int qs = qg*2 + k;
        float a = 0.f;
        #pragma unroll
        for (int f = 0; f < 64; ++f) a = fmaf(sm.p3.agg[qs][f], dW1[f*HD + h], a);
        sm.p3.h1s[qs][h] = fmaxf(a * sm.p3.inv[qs] + db1[h], 0.f);
      }
    }
    __syncthreads();
    if (t < 12) {
      int qs = t / 3, o = t % 3;
      float a = db2[o];
      #pragma unroll
      for (int h = 0; h < HD; ++h) a = fmaf(sm.p3.h1s[qs][h], dW2[h*3 + o], a);
      out[(qb + qs)*3 + o] = a;
    }
  }
}

extern "C" void kernel_launch(void* const* d_in, const int* in_sizes, int n_in,
                              void* d_out, int out_size, void* d_ws, size_t ws_size,
                              hipStream_t stream) {
  const float* qp   = (const float*)d_in[0];
  const float* nf   = (const float*)d_in[1];
  const float* npos = (const float*)d_in[2];
  const float* aW1  = (const float*)d_in[3];
  const float* ab1  = (const float*)d_in[4];
  const float* aW2  = (const float*)d_in[5];
  const float* ab2  = (const float*)d_in[6];
  const float* dW1  = (const float*)d_in[7];
  const float* db1  = (const float*)d_in[8];
  const float* dW2  = (const float*)d_in[9];
  const float* db2  = (const float*)d_in[10];

  float* ws    = (float*)d_ws;
  float* B     = ws + OFF_B;
  float* vb    = ws + OFF_VB;
  float* L     = ws + OFF_L;
  float* pm    = ws + OFF_PM;
  float* part  = ws + OFF_PART;
  float* spart = ws + OFF_SPART;
  unsigned* cnt = (unsigned*)(ws + OFF_CNT);
  float* out   = (float*)d_out;

  hipMemsetAsync(cnt, 0, sizeof(unsigned), stream);
  hipLaunchKernelGGL(fused_all, dim3(NBLK), dim3(256), 0, stream,
                     qp, nf, npos, aW1, ab1, aW2, ab2, dW1, db1, dW2, db2,
                     B, vb, L, pm, part, spart, cnt, out);
}

// Round 13
// 218.423 us; speedup vs baseline: 2.7203x; 2.7203x over previous
//
#include <hip/hip_runtime.h>
#include <math.h>

#define QN 4096
#define NN 1024
#define FD 64
#define HD 128

typedef float v2f __attribute__((ext_vector_type(2)));
typedef float v4f __attribute__((ext_vector_type(4)));

// workspace layout (float offsets)
#define OFF_UT4   0                      // UT4 [32 h4][4096 q][4]
#define OFF_B     524288                 // B   [1024 n][128 h]
#define OFF_VU    655360                 // vu  [4096 q]
#define OFF_VB    659456                 // vb  [1024 n]
#define OFF_L     660480                 // L   [1024 n][4096 q]
#define OFF_PM    4854784                // pm  [64 tile][4096 q]
#define OFF_PART  5116928                // part[8 c][4096 q][64 f]
#define OFF_SPART 7214080                // spart[8 c][4096 q]
#define OFF_DONE  7246848                // done[128] u32
// end: 7246976 floats ~= 29.0 MB

// ---------------- K0: fused prep: UT4, B, vb, vu (R7 verbatim) ----------------
__global__ __launch_bounds__(256) void k0_prep(
    const float* __restrict__ qp, const float* __restrict__ nf,
    const float* __restrict__ npos, const float* __restrict__ aW1,
    const float* __restrict__ ab1, const float* __restrict__ aW2,
    float* __restrict__ B, float* __restrict__ UT4,
    float* __restrict__ vu, float* __restrict__ vb) {
  int bid = blockIdx.x, t = threadIdx.x;
  if (bid < 2048) {
    // UT4[h4][q][j]: flat idx = h4*16384 + q*4 + j ; h = h4*4+j
    int idx = bid * 256 + t;
    int j = idx & 3, q = (idx >> 2) & 4095, h4 = idx >> 14;
    int h = h4 * 4 + j;
    float u = qp[q*3+0] * aW1[(FD+0)*HD + h]
            + qp[q*3+1] * aW1[(FD+1)*HD + h]
            + qp[q*3+2] * aW1[(FD+2)*HD + h];
    UT4[idx] = u;
  } else if (bid < 2560) {
    int i2 = (bid - 2048) * 256 + t;
    int n = i2 >> 7, h = i2 & 127;
    float s = ab1[h];
    #pragma unroll
    for (int f = 0; f < FD; ++f) s = fmaf(nf[n*FD+f], aW1[f*HD+h], s);
    s -= npos[n*3+0] * aW1[(FD+0)*HD + h]
       + npos[n*3+1] * aW1[(FD+1)*HD + h]
       + npos[n*3+2] * aW1[(FD+2)*HD + h];
    B[i2] = s;
    float pv = s * aW2[h];
    #pragma unroll
    for (int m = 1; m < 64; m <<= 1) pv += __shfl_xor(pv, m, 64);
    __shared__ float ps[4];
    if ((t & 63) == 0) ps[t >> 6] = pv;
    __syncthreads();
    if (t == 0)   vb[n] = ps[0] + ps[1];
    if (t == 128) vb[n] = ps[2] + ps[3];
  } else {
    int q = (bid - 2560) * 256 + t;
    float q0 = qp[q*3+0], q1 = qp[q*3+1], q2 = qp[q*3+2];
    float acc = 0.f;
    #pragma unroll
    for (int h = 0; h < HD; ++h) {
      float u = q0 * aW1[(FD+0)*HD + h]
              + q1 * aW1[(FD+1)*HD + h]
              + q2 * aW1[(FD+2)*HD + h];
      acc = fmaf(aW2[h], u, acc);
    }
    vu[q] = acc;
  }
}

// ---------------- K2: logits (R7 verbatim, measured 46.7 us) ----------------
#define LOADU(dst) { \
  _Pragma("unroll") for (int qq = 0; qq < 4; ++qq) { \
    dst[qq][0] = p0[qq*64]; \
    dst[qq][1] = p1[qq*64]; } \
  p0 += 8192; p1 += 8192; }

#define COMPUTE(u) { \
  _Pragma("unroll") for (int nn = 0; nn < 4; ++nn) { \
    v4f b0 = bsb[(nb + nn)*32]; \
    v4f b1 = bsb[(nb + nn)*32 + 1]; \
    v2f b01 = __builtin_shufflevector(b0, b0, 0, 1); \
    v2f b23 = __builtin_shufflevector(b0, b0, 2, 3); \
    v2f b45 = __builtin_shufflevector(b1, b1, 0, 1); \
    v2f b67 = __builtin_shufflevector(b1, b1, 2, 3); \
    _Pragma("unroll") for (int qq = 0; qq < 4; ++qq) { \
      v2f u01 = __builtin_shufflevector(u[qq][0], u[qq][0], 0, 1); \
      v2f u23 = __builtin_shufflevector(u[qq][0], u[qq][0], 2, 3); \
      v2f u45 = __builtin_shufflevector(u[qq][1], u[qq][1], 0, 1); \
      v2f u67 = __builtin_shufflevector(u[qq][1], u[qq][1], 2, 3); \
      v2f t0, t1, t2, t3; \
      asm("v_pk_add_f32 %0, %1, %2" : "=v"(t0) : "v"(u01), "v"(b01)); \
      asm("v_pk_add_f32 %0, %1, %2" : "=v"(t1) : "v"(u23), "v"(b23)); \
      asm("v_pk_add_f32 %0, %1, %2" : "=v"(t2) : "v"(u45), "v"(b45)); \
      asm("v_pk_add_f32 %0, %1, %2" : "=v"(t3) : "v"(u67), "v"(b67)); \
      float a = acc[qq][nn]; \
      a = fmaf(aw[0], __builtin_fabsf(t0.x), a); \
      a = fmaf(aw[1], __builtin_fabsf(t0.y), a); \
      a = fmaf(aw[2], __builtin_fabsf(t1.x), a); \
      a = fmaf(aw[3], __builtin_fabsf(t1.y), a); \
      a = fmaf(aw[4], __builtin_fabsf(t2.x), a); \
      a = fmaf(aw[5], __builtin_fabsf(t2.y), a); \
      a = fmaf(aw[6], __builtin_fabsf(t3.x), a); \
      a = fmaf(aw[7], __builtin_fabsf(t3.y), a); \
      acc[qq][nn] = a; } } \
  bsb += 2; aw += 8; }

__global__ __launch_bounds__(256) void k2_logits(
    const float* __restrict__ Bg, const float* __restrict__ UT4,
    const float* __restrict__ aW2, const float* __restrict__ ab2,
    const float* __restrict__ qp, const float* __restrict__ npos,
    const float* __restrict__ vu, const float* __restrict__ vb,
    float* __restrict__ L, float* __restrict__ pm) {
  __shared__ float Bs[16 * HD];      // 8 KB
  __shared__ float red[4][4][64];    // 4 KB
  const int q0 = blockIdx.x * 256, n0 = blockIdx.y * 16;
  const int t = threadIdx.x;
  {
    const float4* src = (const float4*)(Bg + n0 * HD);
    float4* dst = (float4*)Bs;
    #pragma unroll
    for (int r = 0; r < 2; ++r) dst[r*256 + t] = src[r*256 + t];
  }
  __syncthreads();
  const int lane = t & 63, w = t >> 6;
  const int nb = w * 4;

  float acc[4][4];
  #pragma unroll
  for (int qq = 0; qq < 4; ++qq)
    #pragma unroll
    for (int nn = 0; nn < 4; ++nn) acc[qq][nn] = 0.f;

  const v4f* p0 = (const v4f*)UT4 + q0 + lane;   // h4 even chunk
  const v4f* p1 = p0 + 4096;                     // h4 odd chunk
  const v4f* bsb = (const v4f*)Bs;
  const float* aw = aW2;

  v4f uA[4][2], uB4[4][2];
  LOADU(uA);
  #pragma unroll 1
  for (int hc = 0; hc < 14; hc += 2) {
    LOADU(uB4);
    COMPUTE(uA);
    LOADU(uA);
    COMPUTE(uB4);
  }
  LOADU(uB4);
  COMPUTE(uA);
  COMPUTE(uB4);

  const float bias2 = ab2[0];
  float qx[4], qy[4], vuq[4], m4[4];
  #pragma unroll
  for (int qq = 0; qq < 4; ++qq) {
    int q = q0 + qq*64 + lane;
    qx[qq] = qp[q*3+0];
    qy[qq] = qp[q*3+1];
    vuq[qq] = vu[q];
    m4[qq] = -3.4e38f;
  }
  #pragma unroll
  for (int nn = 0; nn < 4; ++nn) {
    int n = n0 + nb + nn;
    float px = npos[n*3+0], py = npos[n*3+1];
    float vbn = vb[n];
    #pragma unroll
    for (int qq = 0; qq < 4; ++qq) {
      float dx = qx[qq] - px, dy = qy[qq] - py;
      float wgt = 1.f / (sqrtf(dx*dx + dy*dy) + 1e-6f);
      float score = fmaf(0.5f, vuq[qq] + vbn + acc[qq][nn], bias2);
      float lg = score * wgt;
      L[n * QN + q0 + qq*64 + lane] = lg;
      m4[qq] = fmaxf(m4[qq], lg);
    }
  }
  #pragma unroll
  for (int qq = 0; qq < 4; ++qq) red[w][qq][lane] = m4[qq];
  __syncthreads();
  {
    int qq = t >> 6, ll = t & 63;
    float mm = fmaxf(fmaxf(red[0][qq][ll], red[1][qq][ll]),
                     fmaxf(red[2][qq][ll], red[3][qq][ll]));
    pm[blockIdx.y * QN + q0 + qq*64 + ll] = mm;
  }
}

// ---------------- KB: agg (R8 k4) + last-block-decodes (k5 fused) ----------
// 1024 blocks = 128 qt x 8 c; lane: qi=lane&31 (q), fh=lane>>5 (f-half)
__global__ __launch_bounds__(256) void kB_aggdec(
    const float* __restrict__ L, const float* __restrict__ pm,
    const float* __restrict__ nf,
    const float* __restrict__ dW1, const float* __restrict__ db1,
    const float* __restrict__ dW2, const float* __restrict__ db2,
    float* __restrict__ part, float* __restrict__ spart,
    unsigned* __restrict__ done, float* __restrict__ out) {
  __shared__ union {
    struct { float red[4][2][32][33]; float sred[4][33]; } p2;
    struct { float agg[32][65]; float inv[32]; float h1s[32][128]; } p3;
  } sm;
  __shared__ int isLast;
  int b = blockIdx.x;
  int qt = b & 127, c = b >> 7;        // c in [0,8)
  int t = threadIdx.x, lane = t & 63, w = t >> 6;
  int qi = lane & 31, fh = lane >> 5;
  int q = qt * 32 + qi;

  float m = -3.4e38f;
  #pragma unroll
  for (int k = 0; k < 64; ++k) m = fmaxf(m, pm[k * QN + q]);

  float acc[32];
  #pragma unroll
  for (int f = 0; f < 32; ++f) acc[f] = 0.f;
  float s = 0.f;

  int nbase = c * 128 + w * 32;
  const float* Lp = L + (size_t)nbase * QN + q;
  float cur = *Lp;
  for (int i = 0; i < 32; ++i) {
    float nxt = (i < 31) ? Lp[(size_t)(i + 1) * QN] : 0.f;
    float p = exp2f((cur - m) * 1.44269504088896f);
    s += p;
    const float4* nfr = (const float4*)(nf + (nbase + i) * FD + fh * 32);
    #pragma unroll
    for (int g = 0; g < 8; ++g) {
      float4 a = nfr[g];
      acc[g*4+0] = fmaf(p, a.x, acc[g*4+0]);
      acc[g*4+1] = fmaf(p, a.y, acc[g*4+1]);
      acc[g*4+2] = fmaf(p, a.z, acc[g*4+2]);
      acc[g*4+3] = fmaf(p, a.w, acc[g*4+3]);
    }
    cur = nxt;
  }

  #pragma unroll
  for (int fi = 0; fi < 32; ++fi) sm.p2.red[w][fh][fi][qi] = acc[fi];
  if (fh == 0) sm.p2.sred[w][qi] = s;
  __syncthreads();
  #pragma unroll
  for (int k = 0; k < 8; ++k) {
    int idx = k * 256 + t;
    int qq = idx >> 6, f = idx & 63;
    int f1 = f >> 5, f0 = f & 31;
    float sum = sm.p2.red[0][f1][f0][qq] + sm.p2.red[1][f1][f0][qq]
              + sm.p2.red[2][f1][f0][qq] + sm.p2.red[3][f1][f0][qq];
    part[((size_t)c * QN + qt*32 + qq) * 64 + f] = sum;
  }
  if (t < 32) {
    spart[c * QN + qt*32 + t] = sm.p2.sred[0][t] + sm.p2.sred[1][t]
                              + sm.p2.sred[2][t] + sm.p2.sred[3][t];
  }

  // ---- completion: 8th arriving block for this qt runs the decoder ----
  __threadfence();          // make this block's part/spart device-visible
  __syncthreads();          // all threads' stores issued before signal
  if (t == 0) {
    unsigned old = __hip_atomic_fetch_add(&done[qt], 1u, __ATOMIC_ACQ_REL,
                                          __HIP_MEMORY_SCOPE_AGENT);
    isLast = (old == 7);
  }
  __syncthreads();
  if (!isLast) return;
  __threadfence();          // acquire: see other blocks' part/spart

  const int qb = qt * 32;
  {
    int f = t & 63, qh = t >> 6;   // qh in [0,4)
    #pragma unroll
    for (int k = 0; k < 8; ++k) {
      int qs = qh * 8 + k;
      float v = 0.f;
      #pragma unroll
      for (int cc = 0; cc < 8; ++cc)
        v += part[((size_t)cc * QN + qb + qs) * 64 + f];
      sm.p3.agg[qs][f] = v;
    }
  }
  if (t < 32) {
    float ssum = 0.f;
    #pragma unroll
    for (int cc = 0; cc < 8; ++cc) ssum += spart[cc * QN + qb + t];
    sm.p3.inv[t] = 1.f / ssum;
  }
  __syncthreads();
  {
    int h = t & 127, qg = t >> 7;  // qg in [0,2)
    #pragma unroll
    for (int k = 0; k < 16; ++k) {
      int qs = qg * 16 + k;
      float a = 0.f;
      #pragma unroll
      for (int f = 0; f < 64; ++f) a = fmaf(sm.p3.agg[qs][f], dW1[f*HD + h], a);
      sm.p3.h1s[qs][h] = fmaxf(a * sm.p3.inv[qs] + db1[h], 0.f);
    }
  }
  __syncthreads();
  if (t < 96) {
    int qs = t / 3, o = t % 3;
    float a = db2[o];
    #pragma unroll
    for (int h = 0; h < HD; ++h) a = fmaf(sm.p3.h1s[qs][h], dW2[h*3 + o], a);
    out[(qb + qs)*3 + o] = a;
  }
}

extern "C" void kernel_launch(void* const* d_in, const int* in_sizes, int n_in,
                              void* d_out, int out_size, void* d_ws, size_t ws_size,
                              hipStream_t stream) {
  const float* qp   = (const float*)d_in[0];
  const float* nf   = (const float*)d_in[1];
  const float* npos = (const float*)d_in[2];
  const float* aW1  = (const float*)d_in[3];
  const float* ab1  = (const float*)d_in[4];
  const float* aW2  = (const float*)d_in[5];
  const float* ab2  = (const float*)d_in[6];
  const float* dW1  = (const float*)d_in[7];
  const float* db1  = (const float*)d_in[8];
  const float* dW2  = (const float*)d_in[9];
  const float* db2  = (const float*)d_in[10];

  float* ws    = (float*)d_ws;
  float* UT4   = ws + OFF_UT4;
  float* B     = ws + OFF_B;
  float* vu    = ws + OFF_VU;
  float* vb    = ws + OFF_VB;
  float* L     = ws + OFF_L;
  float* pm    = ws + OFF_PM;
  float* part  = ws + OFF_PART;
  float* spart = ws + OFF_SPART;
  unsigned* done = (unsigned*)(ws + OFF_DONE);
  float* out   = (float*)d_out;

  hipMemsetAsync(done, 0, 128 * sizeof(unsigned), stream);
  hipLaunchKernelGGL(k0_prep, dim3(2576), dim3(256), 0, stream,
                     qp, nf, npos, aW1, ab1, aW2, B, UT4, vu, vb);
  hipLaunchKernelGGL(k2_logits, dim3(16, 64), dim3(256), 0, stream,
                     B, UT4, aW2, ab2, qp, npos, vu, vb, L, pm);
  hipLaunchKernelGGL(kB_aggdec, dim3(1024), dim3(256), 0, stream,
                     L, pm, nf, dW1, db1, dW2, db2, part, spart, done, out);
}

// Round 14
// 104.966 us; speedup vs baseline: 5.6607x; 2.0809x over previous
//
#include <hip/hip_runtime.h>
#include <math.h>

#define QN 4096
#define NN 1024
#define FD 64
#define HD 128

typedef float v2f __attribute__((ext_vector_type(2)));
typedef float v4f __attribute__((ext_vector_type(4)));

// workspace layout (float offsets)
#define OFF_UT4   0                      // UT4 [32 h4][4096 q][4]
#define OFF_B     524288                 // B   [1024 n][128 h]
#define OFF_VU    655360                 // vu  [4096 q]
#define OFF_VB    659456                 // vb  [1024 n]
#define OFF_L     660480                 // L   [1024 n][4096 q]
#define OFF_PM    4854784                // pm  [64 tile][4096 q]
#define OFF_PART  5116928                // part[8 c][4096 q][64 f]
#define OFF_SPART 7214080                // spart[8 c][4096 q]
// end: 7246848 floats = 29.0 MB

// ---------------- K0: fused prep: UT4, B, vb, vu (R7 verbatim) ----------------
__global__ __launch_bounds__(256) void k0_prep(
    const float* __restrict__ qp, const float* __restrict__ nf,
    const float* __restrict__ npos, const float* __restrict__ aW1,
    const float* __restrict__ ab1, const float* __restrict__ aW2,
    float* __restrict__ B, float* __restrict__ UT4,
    float* __restrict__ vu, float* __restrict__ vb) {
  int bid = blockIdx.x, t = threadIdx.x;
  if (bid < 2048) {
    int idx = bid * 256 + t;
    int j = idx & 3, q = (idx >> 2) & 4095, h4 = idx >> 14;
    int h = h4 * 4 + j;
    float u = qp[q*3+0] * aW1[(FD+0)*HD + h]
            + qp[q*3+1] * aW1[(FD+1)*HD + h]
            + qp[q*3+2] * aW1[(FD+2)*HD + h];
    UT4[idx] = u;
  } else if (bid < 2560) {
    int i2 = (bid - 2048) * 256 + t;
    int n = i2 >> 7, h = i2 & 127;
    float s = ab1[h];
    #pragma unroll
    for (int f = 0; f < FD; ++f) s = fmaf(nf[n*FD+f], aW1[f*HD+h], s);
    s -= npos[n*3+0] * aW1[(FD+0)*HD + h]
       + npos[n*3+1] * aW1[(FD+1)*HD + h]
       + npos[n*3+2] * aW1[(FD+2)*HD + h];
    B[i2] = s;
    float pv = s * aW2[h];
    #pragma unroll
    for (int m = 1; m < 64; m <<= 1) pv += __shfl_xor(pv, m, 64);
    __shared__ float ps[4];
    if ((t & 63) == 0) ps[t >> 6] = pv;
    __syncthreads();
    if (t == 0)   vb[n] = ps[0] + ps[1];
    if (t == 128) vb[n] = ps[2] + ps[3];
  } else {
    int q = (bid - 2560) * 256 + t;
    float q0 = qp[q*3+0], q1 = qp[q*3+1], q2 = qp[q*3+2];
    float acc = 0.f;
    #pragma unroll
    for (int h = 0; h < HD; ++h) {
      float u = q0 * aW1[(FD+0)*HD + h]
              + q1 * aW1[(FD+1)*HD + h]
              + q2 * aW1[(FD+2)*HD + h];
      acc = fmaf(aW2[h], u, acc);
    }
    vu[q] = acc;
  }
}

// ---------------- K2: logits (R7 verbatim, measured 46.7 us) ----------------
#define LOADU(dst) { \
  _Pragma("unroll") for (int qq = 0; qq < 4; ++qq) { \
    dst[qq][0] = p0[qq*64]; \
    dst[qq][1] = p1[qq*64]; } \
  p0 += 8192; p1 += 8192; }

#define COMPUTE(u) { \
  _Pragma("unroll") for (int nn = 0; nn < 4; ++nn) { \
    v4f b0 = bsb[(nb + nn)*32]; \
    v4f b1 = bsb[(nb + nn)*32 + 1]; \
    v2f b01 = __builtin_shufflevector(b0, b0, 0, 1); \
    v2f b23 = __builtin_shufflevector(b0, b0, 2, 3); \
    v2f b45 = __builtin_shufflevector(b1, b1, 0, 1); \
    v2f b67 = __builtin_shufflevector(b1, b1, 2, 3); \
    _Pragma("unroll") for (int qq = 0; qq < 4; ++qq) { \
      v2f u01 = __builtin_shufflevector(u[qq][0], u[qq][0], 0, 1); \
      v2f u23 = __builtin_shufflevector(u[qq][0], u[qq][0], 2, 3); \
      v2f u45 = __builtin_shufflevector(u[qq][1], u[qq][1], 0, 1); \
      v2f u67 = __builtin_shufflevector(u[qq][1], u[qq][1], 2, 3); \
      v2f t0, t1, t2, t3; \
      asm("v_pk_add_f32 %0, %1, %2" : "=v"(t0) : "v"(u01), "v"(b01)); \
      asm("v_pk_add_f32 %0, %1, %2" : "=v"(t1) : "v"(u23), "v"(b23)); \
      asm("v_pk_add_f32 %0, %1, %2" : "=v"(t2) : "v"(u45), "v"(b45)); \
      asm("v_pk_add_f32 %0, %1, %2" : "=v"(t3) : "v"(u67), "v"(b67)); \
      float a = acc[qq][nn]; \
      a = fmaf(aw[0], __builtin_fabsf(t0.x), a); \
      a = fmaf(aw[1], __builtin_fabsf(t0.y), a); \
      a = fmaf(aw[2], __builtin_fabsf(t1.x), a); \
      a = fmaf(aw[3], __builtin_fabsf(t1.y), a); \
      a = fmaf(aw[4], __builtin_fabsf(t2.x), a); \
      a = fmaf(aw[5], __builtin_fabsf(t2.y), a); \
      a = fmaf(aw[6], __builtin_fabsf(t3.x), a); \
      a = fmaf(aw[7], __builtin_fabsf(t3.y), a); \
      acc[qq][nn] = a; } } \
  bsb += 2; aw += 8; }

__global__ __launch_bounds__(256) void k2_logits(
    const float* __restrict__ Bg, const float* __restrict__ UT4,
    const float* __restrict__ aW2, const float* __restrict__ ab2,
    const float* __restrict__ qp, const float* __restrict__ npos,
    const float* __restrict__ vu, const float* __restrict__ vb,
    float* __restrict__ L, float* __restrict__ pm) {
  __shared__ float Bs[16 * HD];      // 8 KB
  __shared__ float red[4][4][64];    // 4 KB
  const int q0 = blockIdx.x * 256, n0 = blockIdx.y * 16;
  const int t = threadIdx.x;
  {
    const float4* src = (const float4*)(Bg + n0 * HD);
    float4* dst = (float4*)Bs;
    #pragma unroll
    for (int r = 0; r < 2; ++r) dst[r*256 + t] = src[r*256 + t];
  }
  __syncthreads();
  const int lane = t & 63, w = t >> 6;
  const int nb = w * 4;

  float acc[4][4];
  #pragma unroll
  for (int qq = 0; qq < 4; ++qq)
    #pragma unroll
    for (int nn = 0; nn < 4; ++nn) acc[qq][nn] = 0.f;

  const v4f* p0 = (const v4f*)UT4 + q0 + lane;   // h4 even chunk
  const v4f* p1 = p0 + 4096;                     // h4 odd chunk
  const v4f* bsb = (const v4f*)Bs;
  const float* aw = aW2;

  v4f uA[4][2], uB4[4][2];
  LOADU(uA);
  #pragma unroll 1
  for (int hc = 0; hc < 14; hc += 2) {
    LOADU(uB4);
    COMPUTE(uA);
    LOADU(uA);
    COMPUTE(uB4);
  }
  LOADU(uB4);
  COMPUTE(uA);
  COMPUTE(uB4);

  const float bias2 = ab2[0];
  float qx[4], qy[4], vuq[4], m4[4];
  #pragma unroll
  for (int qq = 0; qq < 4; ++qq) {
    int q = q0 + qq*64 + lane;
    qx[qq] = qp[q*3+0];
    qy[qq] = qp[q*3+1];
    vuq[qq] = vu[q];
    m4[qq] = -3.4e38f;
  }
  #pragma unroll
  for (int nn = 0; nn < 4; ++nn) {
    int n = n0 + nb + nn;
    float px = npos[n*3+0], py = npos[n*3+1];
    float vbn = vb[n];
    #pragma unroll
    for (int qq = 0; qq < 4; ++qq) {
      float dx = qx[qq] - px, dy = qy[qq] - py;
      float wgt = 1.f / (sqrtf(dx*dx + dy*dy) + 1e-6f);
      float score = fmaf(0.5f, vuq[qq] + vbn + acc[qq][nn], bias2);
      float lg = score * wgt;
      L[n * QN + q0 + qq*64 + lane] = lg;
      m4[qq] = fmaxf(m4[qq], lg);
    }
  }
  #pragma unroll
  for (int qq = 0; qq < 4; ++qq) red[w][qq][lane] = m4[qq];
  __syncthreads();
  {
    int qq = t >> 6, ll = t & 63;
    float mm = fmaxf(fmaxf(red[0][qq][ll], red[1][qq][ll]),
                     fmaxf(red[2][qq][ll], red[3][qq][ll]));
    pm[blockIdx.y * QN + q0 + qq*64 + ll] = mm;
  }
}

// ---------------- K4: exp + partial aggregate (R8 v2 + 4-deep prefetch) -----
// 1024 blocks = 128 qt x 8 c; lane: qi=lane&31 (q), fh=lane>>5 (f-half)
__global__ __launch_bounds__(256) void k4_agg(
    const float* __restrict__ L, const float* __restrict__ pm,
    const float* __restrict__ nf, float* __restrict__ part,
    float* __restrict__ spart) {
  __shared__ float red[4][2][32][33];   // padded
  __shared__ float sred[4][33];
  int b = blockIdx.x;
  int qt = b & 127, c = b >> 7;        // c in [0,8)
  int t = threadIdx.x, lane = t & 63, w = t >> 6;
  int qi = lane & 31, fh = lane >> 5;
  int q = qt * 32 + qi;

  float m = -3.4e38f;
  #pragma unroll
  for (int k = 0; k < 64; ++k) m = fmaxf(m, pm[k * QN + q]);

  float acc[32];
  #pragma unroll
  for (int f = 0; f < 32; ++f) acc[f] = 0.f;
  float s = 0.f;

  int nbase = c * 128 + w * 32;
  const float* Lp = L + (size_t)nbase * QN + q;

  float pre[4];
  #pragma unroll
  for (int j = 0; j < 4; ++j) pre[j] = Lp[(size_t)j * QN];

  #pragma unroll 4
  for (int i = 0; i < 32; ++i) {
    float cur = pre[i & 3];
    if (i < 28) pre[i & 3] = Lp[(size_t)(i + 4) * QN];
    float p = exp2f((cur - m) * 1.44269504088896f);
    s += p;
    const float4* nfr = (const float4*)(nf + (nbase + i) * FD + fh * 32);
    #pragma unroll
    for (int g = 0; g < 8; ++g) {
      float4 a = nfr[g];
      acc[g*4+0] = fmaf(p, a.x, acc[g*4+0]);
      acc[g*4+1] = fmaf(p, a.y, acc[g*4+1]);
      acc[g*4+2] = fmaf(p, a.z, acc[g*4+2]);
      acc[g*4+3] = fmaf(p, a.w, acc[g*4+3]);
    }
  }

  #pragma unroll
  for (int fi = 0; fi < 32; ++fi) red[w][fh][fi][qi] = acc[fi];
  if (fh == 0) sred[w][qi] = s;
  __syncthreads();
  #pragma unroll
  for (int k = 0; k < 8; ++k) {
    int idx = k * 256 + t;
    int qq = idx >> 6, f = idx & 63;
    int f1 = f >> 5, f0 = f & 31;
    float sum = red[0][f1][f0][qq] + red[1][f1][f0][qq]
              + red[2][f1][f0][qq] + red[3][f1][f0][qq];
    part[((size_t)c * QN + qt*32 + qq) * 64 + f] = sum;
  }
  if (t < 32) {
    spart[c * QN + qt*32 + t] = sred[0][t] + sred[1][t] + sred[2][t] + sred[3][t];
  }
}

// ---------------- K5: reduce partials, normalize, decode (R7 verbatim) ------
__global__ __launch_bounds__(256) void k5_dec(
    const float* __restrict__ part, const float* __restrict__ spart,
    const float* __restrict__ dW1, const float* __restrict__ db1,
    const float* __restrict__ dW2, const float* __restrict__ db2,
    float* __restrict__ out) {
  __shared__ float agg[16][64];
  __shared__ float inv[16];
  __shared__ float h1s[16][128];
  int t = threadIdx.x;
  int qb = blockIdx.x * 16;
  if (t < 16) {
    float s = 0.f;
    #pragma unroll
    for (int c = 0; c < 8; ++c) s += spart[c*QN + qb + t];
    inv[t] = 1.f / s;
  }
  {
    int f = t & 63, qh = t >> 6;
    #pragma unroll
    for (int pass = 0; pass < 4; ++pass) {
      int qs = pass*4 + qh;
      float v = 0.f;
      #pragma unroll
      for (int c = 0; c < 8; ++c) v += part[((size_t)c*QN + qb + qs)*64 + f];
      agg[qs][f] = v;
    }
  }
  __syncthreads();
  {
    int h = t & 127, qg = t >> 7;
    #pragma unroll
    for (int k = 0; k < 8; ++k) {
      int qs = qg*8 + k;
      float a = 0.f;
      #pragma unroll
      for (int f = 0; f < 64; ++f) a = fmaf(agg[qs][f], dW1[f*HD + h], a);
      h1s[qs][h] = fmaxf(a * inv[qs] + db1[h], 0.f);
    }
  }
  __syncthreads();
  if (t < 48) {
    int qs = t / 3, o = t % 3;
    float a = db2[o];
    #pragma unroll
    for (int h = 0; h < HD; ++h) a = fmaf(h1s[qs][h], dW2[h*3 + o], a);
    out[(qb + qs)*3 + o] = a;
  }
}

extern "C" void kernel_launch(void* const* d_in, const int* in_sizes, int n_in,
                              void* d_out, int out_size, void* d_ws, size_t ws_size,
                              hipStream_t stream) {
  const float* qp   = (const float*)d_in[0];
  const float* nf   = (const float*)d_in[1];
  const float* npos = (const float*)d_in[2];
  const float* aW1  = (const float*)d_in[3];
  const float* ab1  = (const float*)d_in[4];
  const float* aW2  = (const float*)d_in[5];
  const float* ab2  = (const float*)d_in[6];
  const float* dW1  = (const float*)d_in[7];
  const float* db1  = (const float*)d_in[8];
  const float* dW2  = (const float*)d_in[9];
  const float* db2  = (const float*)d_in[10];

  float* ws    = (float*)d_ws;
  float* UT4   = ws + OFF_UT4;
  float* B     = ws + OFF_B;
  float* vu    = ws + OFF_VU;
  float* vb    = ws + OFF_VB;
  float* L     = ws + OFF_L;
  float* pm    = ws + OFF_PM;
  float* part  = ws + OFF_PART;
  float* spart = ws + OFF_SPART;

  hipLaunchKernelGGL(k0_prep, dim3(2576), dim3(256), 0, stream,
                     qp, nf, npos, aW1, ab1, aW2, B, UT4, vu, vb);
  hipLaunchKernelGGL(k2_logits, dim3(16, 64), dim3(256), 0, stream,
                     B, UT4, aW2, ab2, qp, npos, vu, vb, L, pm);
  hipLaunchKernelGGL(k4_agg, dim3(1024), dim3(256), 0, stream, L, pm, nf, part, spart);
  hipLaunchKernelGGL(k5_dec, dim3(256), dim3(256), 0, stream,
                     part, spart, dW1, db1, dW2, db2, (float*)d_out);
}